// Round 9
// baseline (115.989 us; speedup 1.0000x reference)
//
#include <hip/hip_runtime.h>

#define NB 8
#define N1 8192
#define N2 2048
#define C1 256
#define C2 512
#define CO 768   // C1 + C2
#define CCH 4    // channels per interp block

// ws: nn_idx (B*N1*4 ints) + nn_w (B*N1*4 floats) = 2 MB (stride-4 packed
// so the consumer can load int4/float4; slot 3 is a deterministic 0).

// ---------------------------------------------------------------------------
// ASM-PINNED arithmetic (R8-validated). Pinned sequence:
//   nrm2 = (x*x + y*y) + z*z            (stepwise rn)
//   dot  = fma(z,qz, fma(y,qy, x*qx))   (fma chain)
//   d2   = (qq + kk) - 2*dot            (stepwise rn)
// Bit-stable under any loop restructuring; matches the numpy/XLA reference's
// selection behavior (R8: zero membership flips, absmax 0.015625).
// ---------------------------------------------------------------------------
#define NRM2(X, Y, Z) ({                                                   \
    float _s, _t;                                                          \
    asm("v_mul_f32 %0, %2, %2\n\t"                                         \
        "v_mul_f32 %1, %3, %3\n\t"                                         \
        "v_add_f32 %0, %0, %1\n\t"                                         \
        "v_mul_f32 %1, %4, %4\n\t"                                         \
        "v_add_f32 %0, %0, %1"                                             \
        : "=&v"(_s), "=&v"(_t) : "v"(X), "v"(Y), "v"(Z));                  \
    _s; })

#define D2PIN(QX, QY, QZ, QQ, X, Y, Z, KK) ({                              \
    float _d, _t;                                                          \
    asm("v_mul_f32 %0, %2, %5\n\t"        /* qx*kx                  */     \
        "v_fma_f32 %0, %3, %6, %0\n\t"    /* + qy*ky (single-round) */     \
        "v_fma_f32 %0, %4, %7, %0\n\t"    /* + qz*kz (single-round) */     \
        "v_add_f32 %1, %8, %9\n\t"        /* qq+kk                  */     \
        "v_mul_f32 %0, 2.0, %0\n\t"       /* 2*dot                  */     \
        "v_sub_f32 %0, %1, %0"            /* d2                     */     \
        : "=&v"(_d), "=&v"(_t)                                             \
        : "v"(QX), "v"(QY), "v"(QZ), "v"(X), "v"(Y), "v"(Z),               \
          "v"(QQ), "v"(KK));                                               \
    _d; })

// ---------------------------------------------------------------------------
// 4-wave KNN (R8-validated verbatim except the final packed store): block =
// 64 queries; waves stage all 2048 keys, wave w scans keys [w*512,(w+1)*512)
// ascending (lane = query). Chunk-local sorted top-3 merged by tid<64 in
// (chunk asc, rank asc) order with strict-< => identical selection to a
// single ascending scan == jax.lax.top_k (lowest index wins ties).
// ---------------------------------------------------------------------------
__global__ __launch_bounds__(256, 4) void knn_fused(
    const float* __restrict__ qxyz,   // (B, 3, N1)
    const float* __restrict__ kxyz,   // (B, 3, N2)
    int*   __restrict__ nn_idx,       // (B*N1*4) packed
    float* __restrict__ nn_w)         // (B*N1*4) packed
{
    __shared__ __align__(16) float skx[N2];
    __shared__ __align__(16) float sky[N2];
    __shared__ __align__(16) float skz[N2];
    __shared__ __align__(16) float skk[N2];
    __shared__ float pd[4][64][3];
    __shared__ int   pi[4][64][3];

    const int b   = blockIdx.x >> 7;        // 128 tiles of 64 queries
    const int n0  = (blockIdx.x & 127) * 64;
    const int tid = threadIdx.x;
    const int w   = tid >> 6, lane = tid & 63;

    const float* kb = kxyz + (size_t)b * 3 * N2;
    for (int j = tid; j < N2; j += 256) {
        float x = kb[j], y = kb[N2 + j], z = kb[2 * N2 + j];
        skx[j] = x; sky[j] = y; skz[j] = z;
        skk[j] = NRM2(x, y, z);
    }
    __syncthreads();

    const int n = n0 + lane;
    const float* qb = qxyz + (size_t)b * 3 * N1;
    const float qx = qb[n], qy = qb[N1 + n], qz = qb[2 * N1 + n];
    const float qq = NRM2(qx, qy, qz);

    float b0 = 3.4e38f, b1 = 3.4e38f, b2 = 3.4e38f;
    int   i0 = 0, i1 = 0, i2 = 0;

#define PROC(X, Y, Z, KK, J) do {                                          \
        float d2 = D2PIN(qx, qy, qz, qq, (X), (Y), (Z), (KK));             \
        if (d2 < b2) {                                                     \
            bool c0 = d2 < b0, c1 = d2 < b1;                               \
            b2 = c1 ? b1 : d2;               i2 = c1 ? i1 : (J);           \
            b1 = c0 ? b0 : (c1 ? d2 : b1);   i1 = c0 ? i0 : (c1 ? (J) : i1); \
            b0 = c0 ? d2 : b0;               i0 = c0 ? (J) : i0;           \
        }                                                                  \
    } while (0)

    const int jlo = w * (N2 / 4), jhi = jlo + (N2 / 4);
    #pragma unroll 4
    for (int jb = jlo; jb < jhi; jb += 4) {
        float4 x4 = *(const float4*)&skx[jb];
        float4 y4 = *(const float4*)&sky[jb];
        float4 z4 = *(const float4*)&skz[jb];
        float4 k4 = *(const float4*)&skk[jb];
        PROC(x4.x, y4.x, z4.x, k4.x, jb + 0);
        PROC(x4.y, y4.y, z4.y, k4.y, jb + 1);
        PROC(x4.z, y4.z, z4.z, k4.z, jb + 2);
        PROC(x4.w, y4.w, z4.w, k4.w, jb + 3);
    }
#undef PROC

    pd[w][lane][0] = b0; pd[w][lane][1] = b1; pd[w][lane][2] = b2;
    pi[w][lane][0] = i0; pi[w][lane][1] = i1; pi[w][lane][2] = i2;
    __syncthreads();

    if (tid < 64) {
        float m0 = 3.4e38f, m1 = 3.4e38f, m2 = 3.4e38f;
        int   j0 = 0, j1 = 0, j2 = 0;
        #pragma unroll
        for (int c = 0; c < 4; ++c) {
            #pragma unroll
            for (int s = 0; s < 3; ++s) {
                float d = pd[c][tid][s];
                int   i = pi[c][tid][s];
                if (d < m2) {
                    bool c0 = d < m0, c1 = d < m1;
                    m2 = c1 ? m1 : d;                j2 = c1 ? j1 : i;
                    m1 = c0 ? m0 : (c1 ? d : m1);    j1 = c0 ? j0 : (c1 ? i : j1);
                    m0 = c0 ? d : m0;                j0 = c0 ? i  : j0;
                }
            }
        }
        // weights: mirror reference op order (R8-validated math, packed store)
        float d0f = fmaxf(m0, 1e-10f), d1f = fmaxf(m1, 1e-10f), d2f = fmaxf(m2, 1e-10f);
        float v0 = __fdiv_rn(1.0f, d0f), v1 = __fdiv_rn(1.0f, d1f), v2 = __fdiv_rn(1.0f, d2f);
        float s  = __fadd_rn(__fadd_rn(v0, v1), v2);
        const size_t g = (size_t)b * N1 + n0 + tid;
        int4   iv = make_int4(j0, j1, j2, 0);
        float4 wv = make_float4(__fdiv_rn(v0, s), __fdiv_rn(v1, s),
                                __fdiv_rn(v2, s), 0.0f);
        *(int4*)  &nn_idx[g * 4] = iv;
        *(float4*)&nn_w  [g * 4] = wv;
    }
}

// ---------------------------------------------------------------------------
// Fused interp + qfeat copy. Block = (batch, 4-channel group). Stage the 4
// channels as float4-per-key in LDS (32 KB): gather = 3 ds_read_b128 instead
// of 12 ds_read_b32; nn loads = 1 int4 + 1 float4 (16 B/lane, coalesced).
// Channel values and fma op order identical to the R5/R6/R8-validated
// interp3 -> bit-identical output. Copy region folded in per block.
// ---------------------------------------------------------------------------
__global__ __launch_bounds__(256) void interp4(
    const float* __restrict__ kfeat,  // (B, C2, N2)
    const int*   __restrict__ nn_idx, // packed stride-4
    const float* __restrict__ nn_w,   // packed stride-4
    const float* __restrict__ qfeat,  // (B, C1, N1)
    float* __restrict__ out)          // (B, CO, N1)
{
    __shared__ __align__(16) float4 skf[N2];   // 32 KB
    const int b     = blockIdx.x & 7;       // XCD-pinned batch
    const int cg    = blockIdx.x >> 3;      // 0..127
    const int cbase = cg * CCH;
    const int tid   = threadIdx.x;

    const float* kf = kfeat + (size_t)b * C2 * N2 + (size_t)cbase * N2;
    for (int j = tid; j < N2; j += 256) {
        skf[j] = make_float4(kf[j], kf[N2 + j], kf[2 * N2 + j], kf[3 * N2 + j]);
    }
    __syncthreads();

    const int*   ib = nn_idx + (size_t)b * N1 * 4;
    const float* wb = nn_w   + (size_t)b * N1 * 4;
    float* ob = out + (size_t)b * CO * N1;

    #pragma unroll 4
    for (int t = 0; t < N1 / 256; ++t) {
        const int n = t * 256 + tid;
        const int4   iv = *(const int4*)  &ib[(size_t)n * 4];
        const float4 wv = *(const float4*)&wb[(size_t)n * 4];
        const float4 f0 = skf[iv.x];
        const float4 f1 = skf[iv.y];
        const float4 f2 = skf[iv.z];
        // per-channel: fmaf(w2,f2, fmaf(w1,f1, mul(w0,f0))) — validated order
        ob[(size_t)(cbase + 0) * N1 + n] =
            fmaf(wv.z, f2.x, fmaf(wv.y, f1.x, __fmul_rn(wv.x, f0.x)));
        ob[(size_t)(cbase + 1) * N1 + n] =
            fmaf(wv.z, f2.y, fmaf(wv.y, f1.y, __fmul_rn(wv.x, f0.y)));
        ob[(size_t)(cbase + 2) * N1 + n] =
            fmaf(wv.z, f2.z, fmaf(wv.y, f1.z, __fmul_rn(wv.x, f0.z)));
        ob[(size_t)(cbase + 3) * N1 + n] =
            fmaf(wv.z, f2.w, fmaf(wv.y, f1.w, __fmul_rn(wv.x, f0.w)));
    }

    // Fused copy: this block moves float4s [cg*4096, (cg+1)*4096) of the
    // batch's qfeat plane (C1*N1/4 = 524288 = 128 blocks * 4096). Pure
    // float4 stream, same semantics as the validated copy_kernel.
    const float4* qsrc = (const float4*)(qfeat + (size_t)b * C1 * N1);
    float4*       qdst = (float4*)(out + (size_t)b * CO * N1 + (size_t)C2 * N1);
    #pragma unroll
    for (int k = 0; k < 16; ++k) {
        const size_t r = (size_t)cg * 4096 + (size_t)k * 256 + tid;
        qdst[r] = qsrc[r];
    }
}

extern "C" void kernel_launch(void* const* d_in, const int* in_sizes, int n_in,
                              void* d_out, int out_size, void* d_ws, size_t ws_size,
                              hipStream_t stream) {
    const float* qxyz  = (const float*)d_in[0];
    const float* kxyz  = (const float*)d_in[1];
    const float* qfeat = (const float*)d_in[2];
    const float* kfeat = (const float*)d_in[3];
    float* out = (float*)d_out;

    int*   nn_idx = (int*)d_ws;                              // 4*B*N1 ints
    float* nn_w   = (float*)d_ws + (size_t)4 * NB * N1;      // 4*B*N1 floats

    knn_fused<<<NB * (N1 / 64), 256, 0, stream>>>(qxyz, kxyz, nn_idx, nn_w);
    interp4<<<NB * (C2 / CCH), 256, 0, stream>>>(kfeat, nn_idx, nn_w, qfeat, out);
}